// Round 4
// baseline (259.512 us; speedup 1.0000x reference)
//
#include <hip/hip_runtime.h>

// ViT cls-token-only forward. B=16, C=8, D=511, DIM=2048, SEQ=512, NH=16.
// q = (cls+pos0) @ Wq + bq; r[h] = SCALE * Wk_h @ q_h;
// scores[b,h,j] = tok[b,j].r[h]; softmax; u[b,h] = sum_j p tok[b,j];
// ao = u @ Wv + bv; out = ao @ proj_w + proj_b.
//
// R12: shape-matched engines. Insight from R9/R11 counters: total traffic
// (~200 MB = 32 µs at BW) never explained the 221-259 µs — the cost was
// scalar-LDS storms, 4.2M atomics, and MFMA staging for M=16 GEMMs.
//  - tok/tokT materialization dropped (R11's k0 was 63 µs at 37% BW).
//  - k3 (scores): R9's proven MFMA kernel, store changed to plain per-ks
//    partial buffers (R11-proven). Only MFMA kernel left.
//  - k5 (softmax+u): VECTOR kernel. Lane owns a d-quad (float4 coalesced x
//    read, x read exactly once), 16 fp32 accumulators, p broadcast from LDS
//    via uniform-address ds_read_b128 (no conflicts, no scalar reads, no
//    conversions). Softmax fused (fp32 p). j-split 8 ways for parallelism;
//    u written as plain js-partials.
//  - k6/k7 (ao/out): vector kernels, weights read once coalesced; ks/ms
//    k-splits with plain partials summed at next stage's staging. Atomics
//    only in k7's final out accumulate (0.5M vs R9's 4.2M total).
//  - p/u/ao now fp32 (more accurate than bf16 hi/lo). 6 dispatches.

#define BB   16
#define CC   8
#define DD   511
#define DIM  2048
#define SEQ  512
#define NH   16
#define HD   128
#define W3   6144
#define SCALE 0.08838834764831845f

// workspace layout (float offsets)
#define QP_OFF   0            // 64*2048 q partials (plain)
#define G_OFF    131072       // 16 atomic gamma (zeroed by k1)
#define SCP_OFF  131088       // 4*131072 score partials (plain)
#define SCPSZ    131072
#define RB_OFF   655376       // r bf16 hi/lo: 65536 shorts (32768 floats)
#define UP_OFF   688144       // u partials: 8 js * 16 b * 16 h * 2048 fp32
#define AOP_OFF  4882448      // ao partials: 16 ks * 16 b * 2048 fp32
// total = 5,406,736 floats ~= 21.6 MB

typedef __attribute__((ext_vector_type(8))) short short8;
typedef __attribute__((ext_vector_type(4))) float floatx4;

static __device__ inline short bf_hi(float f) {
  return (short)(__float_as_uint(f) >> 16);          // truncate to bf16
}
static __device__ inline float bf_hif(float f) {
  return __uint_as_float(__float_as_uint(f) & 0xffff0000u);
}

// K1: q partials + zeroing. qpart[dc][n] = sum_{d in chunk} t0[d]*Wq[d][n]
// (+bias at dc==0). Zeroes gamma (16) and out (32768). grid (8 nt, 64 dc).
__global__ __launch_bounds__(256) void k1_q(
    const float* __restrict__ pos, const float* __restrict__ cls,
    const float* __restrict__ qkv_w, const float* __restrict__ qkv_b,
    float* __restrict__ ws, float* __restrict__ out) {
  int n  = blockIdx.x * 256 + threadIdx.x;
  int dc = blockIdx.y;
  int tid = (blockIdx.x + blockIdx.y * 8) * 256 + threadIdx.x;  // 0..131071
  if (tid < 16) ws[G_OFF + tid] = 0.f;
  if (tid < BB * DIM) out[tid] = 0.f;
  int d0 = dc * 32;
  float acc = (dc == 0) ? qkv_b[n] : 0.f;
#pragma unroll 8
  for (int d = d0; d < d0 + 32; ++d) {
    float t0 = cls[d] + pos[d];           // uniform -> scalar load
    acc += t0 * qkv_w[(size_t)d * W3 + n];
  }
  ws[QP_OFF + dc * DIM + n] = acc;
}

// K2: r[h][d] = SCALE * (Wk[d, h-slice] . q[h-slice]); q from summing the 64
// k1 partials. Writes bf16 hi/lo r + atomic gamma. grid (16 dtile, 16 h), 128.
__global__ __launch_bounds__(128) void k2_r(
    const float* __restrict__ qkv_w, const float* __restrict__ pos,
    const float* __restrict__ cls, float* __restrict__ ws) {
  __shared__ float qs[HD];
  int h = blockIdx.y;
  int d = blockIdx.x * 128 + threadIdx.x;
  float qa = 0.f;
#pragma unroll 8
  for (int c = 0; c < 64; ++c)
    qa += ws[QP_OFF + c * DIM + h * HD + threadIdx.x];
  qs[threadIdx.x] = qa;
  __syncthreads();
  const float4* w4 = reinterpret_cast<const float4*>(
      qkv_w + (size_t)d * W3 + DIM + h * HD);
  float acc = 0.f;
#pragma unroll 8
  for (int e4 = 0; e4 < 32; ++e4) {
    float4 w = w4[e4];
    acc += qs[e4*4+0]*w.x + qs[e4*4+1]*w.y + qs[e4*4+2]*w.z + qs[e4*4+3]*w.w;
  }
  float r = acc * SCALE;
  int i = h * DIM + d;
  short* rb = (short*)(ws + RB_OFF);
  rb[i] = bf_hi(r);
  rb[NH * DIM + i] = bf_hi(r - bf_hif(r));
  float g = (cls[d] + pos[d]) * r;        // fused gamma partial
  for (int m = 1; m < 64; m <<= 1) g += __shfl_xor(g, m, 64);
  if ((threadIdx.x & 63) == 0) atomicAdd(&ws[G_OFF + h], g);
}

// K3: scores[b,h,j>=1] via MFMA, 3-term hi/lo (R9-proven compute; plain
// per-ks partial stores). grid (8 jt2, 16 b, 4 ks), 256 thr = 4 waves.
__global__ __launch_bounds__(256) void k3_scores_mfma(
    const float* __restrict__ x, const float* __restrict__ pos,
    float* __restrict__ ws) {
  int jt2 = blockIdx.x, b = blockIdx.y, ks = blockIdx.z;
  int t = threadIdx.x;
  int w = t >> 6, l = t & 63;
  int jt = jt2 * 4 + w;
  int m16 = l & 15, kg = l >> 4;
  int jrow = 1 + jt * 16 + m16;
  int jc = jrow < SEQ ? jrow : (SEQ - 1);   // clamp; jrow==512 masked at store
  const size_t xrow = (size_t)b * CC * DD * 256 + (size_t)(jc - 1) * 256;
  const short* rh = (const short*)(ws + RB_OFF);
  const short* rl = rh + NH * DIM;
  floatx4 acc = {0.f, 0.f, 0.f, 0.f};
#pragma unroll 2
  for (int kk = ks * 16; kk < ks * 16 + 16; ++kk) {
    int d0 = kk * 32 + kg * 8;
    int c = d0 >> 8, doff = d0 & 255;
    const float4* xp = reinterpret_cast<const float4*>(
        x + xrow + (size_t)c * DD * 256 + doff);
    const float4* pp = reinterpret_cast<const float4*>(
        pos + (size_t)jc * DIM + d0);
    float4 xa = xp[0], xb = xp[1];
    float4 pa = pp[0], pb = pp[1];
    float f[8] = {xa.x + pa.x, xa.y + pa.y, xa.z + pa.z, xa.w + pa.w,
                  xb.x + pb.x, xb.y + pb.y, xb.z + pb.z, xb.w + pb.w};
    short8 ahi, alo;
#pragma unroll
    for (int i = 0; i < 8; ++i) {
      ahi[i] = bf_hi(f[i]);
      alo[i] = bf_hi(f[i] - bf_hif(f[i]));   // f-hi exact, then truncate
    }
    short8 bhi = *reinterpret_cast<const short8*>(rh + m16 * DIM + d0);
    short8 blo = *reinterpret_cast<const short8*>(rl + m16 * DIM + d0);
    acc = __builtin_amdgcn_mfma_f32_16x16x32_bf16(ahi, bhi, acc, 0, 0, 0);
    acc = __builtin_amdgcn_mfma_f32_16x16x32_bf16(ahi, blo, acc, 0, 0, 0);
    acc = __builtin_amdgcn_mfma_f32_16x16x32_bf16(alo, bhi, acc, 0, 0, 0);
  }
  // C layout: col(h) = l&15, row(j) = (l>>4)*4 + reg  [m89-verified]
  int h = m16;
#pragma unroll
  for (int reg = 0; reg < 4; ++reg) {
    int row = kg * 4 + reg;
    int j = 1 + jt * 16 + row;
    if (j < SEQ)
      ws[SCP_OFF + (size_t)ks * SCPSZ + (size_t)(b * NH + h) * SEQ + j] =
          acc[reg];
  }
}

// K5: fused softmax + u (vector FMA). Block = (dt in {0,1}, b, js in 0..7).
// Softmax: wave w computes full-512 stats for h = w*4..w*4+3, stores fp32
// p slice (64 j) to LDS. u-phase: lane owns d-quad; float4 x/pos reads
// (x read exactly once across grid); p broadcast via uniform ds_read_b128.
// Writes u js-partials (plain). grid (2 dt, 16 b, 8 js), 256 thr.
__global__ __launch_bounds__(256) void k5_pv(
    const float* __restrict__ x, const float* __restrict__ pos,
    const float* __restrict__ cls, float* __restrict__ ws) {
  int dt = blockIdx.x, b = blockIdx.y, js = blockIdx.z, t = threadIdx.x;
  __shared__ __attribute__((aligned(16))) float pT[64][20];  // [j-local][h]
  int w = t >> 6, l = t & 63;
  // ---- softmax: stats over all 512 j; keep slice i == js ----
  for (int rr = 0; rr < 4; ++rr) {
    int h = w * 4 + rr;
    const float* sc0 = ws + SCP_OFF + (size_t)(b * NH + h) * SEQ;
    float gam = ws[G_OFF + h];
    float s[8];
#pragma unroll
    for (int i = 0; i < 8; ++i) {
      int j = i * 64 + l;
      s[i] = sc0[j] + sc0[SCPSZ + j] + sc0[2 * SCPSZ + j] + sc0[3 * SCPSZ + j];
    }
    if (l == 0) s[0] = gam;               // j=0 slot holds the cls score
    float mx = s[0];
#pragma unroll
    for (int i = 1; i < 8; ++i) mx = fmaxf(mx, s[i]);
    for (int m = 1; m < 64; m <<= 1) mx = fmaxf(mx, __shfl_xor(mx, m, 64));
    float e[8], sum = 0.f;
#pragma unroll
    for (int i = 0; i < 8; ++i) { e[i] = __expf(s[i] - mx); sum += e[i]; }
    for (int m = 1; m < 64; m <<= 1) sum += __shfl_xor(sum, m, 64);
    float inv = 1.f / sum;
    pT[l][h] = e[js] * inv;               // j = js*64 + l  (i == js slice)
  }
  __syncthreads();
  // ---- u-phase ----
  int d = dt * 1024 + t * 4;
  int c = d >> 8, doff = d & 255;
  const float* xcol = x + (size_t)b * CC * DD * 256 + (size_t)c * DD * 256 + doff;
  floatx4 acc[16];
#pragma unroll
  for (int h = 0; h < 16; ++h) acc[h] = (floatx4){0.f, 0.f, 0.f, 0.f};
#pragma unroll 4
  for (int jl = 0; jl < 64; ++jl) {
    int j = js * 64 + jl;
    floatx4 pv = *reinterpret_cast<const floatx4*>(pos + (size_t)j * DIM + d);
    floatx4 xv = (j == 0)
        ? *reinterpret_cast<const floatx4*>(cls + d)
        : *reinterpret_cast<const floatx4*>(xcol + (size_t)(j - 1) * 256);
    floatx4 tok = xv + pv;
#pragma unroll
    for (int h4 = 0; h4 < 4; ++h4) {
      floatx4 p4 = *reinterpret_cast<const floatx4*>(&pT[jl][h4 * 4]);
      acc[h4 * 4 + 0] += p4.x * tok;
      acc[h4 * 4 + 1] += p4.y * tok;
      acc[h4 * 4 + 2] += p4.z * tok;
      acc[h4 * 4 + 3] += p4.w * tok;
    }
  }
  float* ub = ws + UP_OFF + (size_t)(js * 16 + b) * 16 * 2048 + d;
#pragma unroll
  for (int h = 0; h < 16; ++h)
    *reinterpret_cast<floatx4*>(ub + (size_t)h * 2048) = acc[h];
}

// K6: ao partials. Block (nt, ks): m-range 256 (heads h0=nt*2, nt*2+1),
// d-range 128. Stage u (summing 8 js-partials) to LDS [hh][dd][b]; loop dd:
// coalesced Wv column load + 16 FMA via uniform b128 broadcast. Plain store
// aop[ks][b][m]. grid (8 nt, 16 ks), 256 thr.
__global__ __launch_bounds__(256) void k6_ao(
    const float* __restrict__ qkv_w, const float* __restrict__ qkv_b,
    float* __restrict__ ws) {
  int nt = blockIdx.x, ks = blockIdx.y, t = threadIdx.x;
  int m = nt * 256 + t;
  int h0 = nt * 2;
  __shared__ __attribute__((aligned(16))) float us[2][128][20];
  for (int s = t; s < 4096; s += 256) {
    int dd = s & 127, bb = (s >> 7) & 15, hh = s >> 11;
    float a = 0.f;
#pragma unroll
    for (int js = 0; js < 8; ++js)
      a += ws[UP_OFF + (size_t)(js * 16 + bb) * 16 * 2048 +
              (size_t)(h0 + hh) * 2048 + ks * 128 + dd];
    us[hh][dd][bb] = a;
  }
  __syncthreads();
  int hl = t >> 7;
  float acc[BB];
#pragma unroll
  for (int bb = 0; bb < BB; ++bb) acc[bb] = 0.f;
  const float* wcol = qkv_w + (size_t)(ks * 128) * W3 + 2 * DIM + m;
#pragma unroll 4
  for (int dd = 0; dd < 128; ++dd) {
    float wv = wcol[(size_t)dd * W3];
    floatx4 u0 = *reinterpret_cast<const floatx4*>(&us[hl][dd][0]);
    floatx4 u1 = *reinterpret_cast<const floatx4*>(&us[hl][dd][4]);
    floatx4 u2 = *reinterpret_cast<const floatx4*>(&us[hl][dd][8]);
    floatx4 u3 = *reinterpret_cast<const floatx4*>(&us[hl][dd][12]);
    acc[0]  += u0.x * wv; acc[1]  += u0.y * wv; acc[2]  += u0.z * wv; acc[3]  += u0.w * wv;
    acc[4]  += u1.x * wv; acc[5]  += u1.y * wv; acc[6]  += u1.z * wv; acc[7]  += u1.w * wv;
    acc[8]  += u2.x * wv; acc[9]  += u2.y * wv; acc[10] += u2.z * wv; acc[11] += u2.w * wv;
    acc[12] += u3.x * wv; acc[13] += u3.y * wv; acc[14] += u3.z * wv; acc[15] += u3.w * wv;
  }
  float bias = (ks == 0) ? qkv_b[2 * DIM + m] : 0.f;
#pragma unroll
  for (int bb = 0; bb < BB; ++bb)
    ws[AOP_OFF + (size_t)(ks * 16 + bb) * 2048 + m] = acc[bb] + bias;
}

// K7: out. Block (nt, ms): n-range 256, m-range 128. Stage ao (summing 16
// ks-partials) to LDS [mm][b]; loop mm: coalesced proj load + 16 FMA via
// uniform b128 broadcast; atomicAdd into out (zeroed by k1).
// grid (8 nt, 16 ms), 256 thr.
__global__ __launch_bounds__(256) void k7_out(
    const float* __restrict__ proj_w, const float* __restrict__ proj_b,
    const float* __restrict__ ws, float* __restrict__ out) {
  int nt = blockIdx.x, ms = blockIdx.y, t = threadIdx.x;
  int n = nt * 256 + t;
  int m0 = ms * 128;
  __shared__ __attribute__((aligned(16))) float as[128][20];
  for (int s = t; s < 2048; s += 256) {
    int mm = s & 127, bb = s >> 7;
    float a = 0.f;
#pragma unroll
    for (int ks = 0; ks < 16; ++ks)
      a += ws[AOP_OFF + (size_t)(ks * 16 + bb) * 2048 + m0 + mm];
    as[mm][bb] = a;
  }
  __syncthreads();
  float acc[BB];
#pragma unroll
  for (int bb = 0; bb < BB; ++bb) acc[bb] = 0.f;
  const float* wcol = proj_w + (size_t)m0 * DIM + n;
#pragma unroll 4
  for (int mm = 0; mm < 128; ++mm) {
    float wv = wcol[(size_t)mm * DIM];
    floatx4 a0 = *reinterpret_cast<const floatx4*>(&as[mm][0]);
    floatx4 a1 = *reinterpret_cast<const floatx4*>(&as[mm][4]);
    floatx4 a2 = *reinterpret_cast<const floatx4*>(&as[mm][8]);
    floatx4 a3 = *reinterpret_cast<const floatx4*>(&as[mm][12]);
    acc[0]  += a0.x * wv; acc[1]  += a0.y * wv; acc[2]  += a0.z * wv; acc[3]  += a0.w * wv;
    acc[4]  += a1.x * wv; acc[5]  += a1.y * wv; acc[6]  += a1.z * wv; acc[7]  += a1.w * wv;
    acc[8]  += a2.x * wv; acc[9]  += a2.y * wv; acc[10] += a2.z * wv; acc[11] += a2.w * wv;
    acc[12] += a3.x * wv; acc[13] += a3.y * wv; acc[14] += a3.z * wv; acc[15] += a3.w * wv;
  }
  float bias = (ms == 0) ? proj_b[n] : 0.f;
#pragma unroll
  for (int bb = 0; bb < BB; ++bb)
    atomicAdd(&out[bb * DIM + n], acc[bb] + bias);
}

extern "C" void kernel_launch(void* const* d_in, const int* in_sizes, int n_in,
                              void* d_out, int out_size, void* d_ws, size_t ws_size,
                              hipStream_t stream) {
  const float* x      = (const float*)d_in[0];
  const float* pos    = (const float*)d_in[1];
  const float* cls    = (const float*)d_in[2];
  const float* qkv_w  = (const float*)d_in[3];
  const float* qkv_b  = (const float*)d_in[4];
  const float* proj_w = (const float*)d_in[5];
  const float* proj_b = (const float*)d_in[6];
  float* ws  = (float*)d_ws;
  float* out = (float*)d_out;

  k1_q          <<<dim3(8, 64),    256, 0, stream>>>(pos, cls, qkv_w, qkv_b, ws, out);
  k2_r          <<<dim3(16, 16),   128, 0, stream>>>(qkv_w, pos, cls, ws);
  k3_scores_mfma<<<dim3(8, 16, 4), 256, 0, stream>>>(x, pos, ws);
  k5_pv         <<<dim3(2, 16, 8), 256, 0, stream>>>(x, pos, cls, ws);
  k6_ao         <<<dim3(8, 16),    256, 0, stream>>>(qkv_w, qkv_b, ws);
  k7_out        <<<dim3(8, 16),    256, 0, stream>>>(proj_w, proj_b, ws, out);
}

// Round 5
// 244.803 us; speedup vs baseline: 1.0601x; 1.0601x over previous
//
#include <hip/hip_runtime.h>

// ViT cls-token-only forward. B=16, C=8, D=511, DIM=2048, SEQ=512, NH=16.
// q = (cls+pos0) @ Wq + bq; r[h] = SCALE * Wk_h @ q_h;
// scores[b,h,j] = tok[b,j].r[h]; softmax; u[b,h] = sum_j p tok[b,j];
// ao = u @ Wv + bv; out = ao @ proj_w + proj_b.
//
// R13: occupancy + redundancy consolidation of R12.
//  Evidence (R11 259.0 vs R12 259.5 identical despite huge structural diff;
//  R8 220.8 vs R9 221.5 ditto): dur is floor-dominated (ws poison fill 40 µs
//  + reset dispatches + launch gaps) + ~70 µs kernel term + container
//  variance. This round shrinks the kernel term:
//  - k4 reinstated (softmax once per (b,h), fp32 p, 1 MB): kills k5's 16x
//    redundant softmax recompute (~128 MB of SCP re-reads through L2/L3).
//  - k5: float2 per lane, grid (4 dt,16 b,8 js) = 512 blocks -> 2 blocks/CU,
//    8 waves/CU (was 1 block/CU, 4 waves). x still read exactly once.
//  - k6/k7: k-splits doubled (32-way) -> 256 blocks = 1 block/CU (was 128
//    blocks = half the CUs idle).
//  - k1/k2/k3 unchanged (proven, individually small).

#define BB   16
#define CC   8
#define DD   511
#define DIM  2048
#define SEQ  512
#define NH   16
#define HD   128
#define W3   6144
#define SCALE 0.08838834764831845f

// workspace layout (float offsets)
#define QP_OFF   0            // 64*2048 q partials (plain)
#define G_OFF    131072       // 16 atomic gamma (zeroed by k1)
#define SCP_OFF  131088       // 4*131072 score partials (plain)
#define SCPSZ    131072
#define RB_OFF   655376       // r bf16 hi/lo: 65536 shorts (32768 floats)
#define PF_OFF   688144       // p fp32: 16b*16h*512 = 131072
#define UP_OFF   819216       // u partials: 8 js * 16 b * 16 h * 2048 fp32
#define AOP_OFF  5013520      // ao partials: 32 ks * 16 b * 2048 fp32
// total = 6,062,096 floats ~= 24.2 MB

typedef __attribute__((ext_vector_type(8))) short short8;
typedef __attribute__((ext_vector_type(4))) float floatx4;
typedef __attribute__((ext_vector_type(2))) float floatx2;

static __device__ inline short bf_hi(float f) {
  return (short)(__float_as_uint(f) >> 16);          // truncate to bf16
}
static __device__ inline float bf_hif(float f) {
  return __uint_as_float(__float_as_uint(f) & 0xffff0000u);
}

// K1: q partials + zeroing. qpart[dc][n] = sum_{d in chunk} t0[d]*Wq[d][n]
// (+bias at dc==0). Zeroes gamma (16) and out (32768). grid (8 nt, 64 dc).
__global__ __launch_bounds__(256) void k1_q(
    const float* __restrict__ pos, const float* __restrict__ cls,
    const float* __restrict__ qkv_w, const float* __restrict__ qkv_b,
    float* __restrict__ ws, float* __restrict__ out) {
  int n  = blockIdx.x * 256 + threadIdx.x;
  int dc = blockIdx.y;
  int tid = (blockIdx.x + blockIdx.y * 8) * 256 + threadIdx.x;  // 0..131071
  if (tid < 16) ws[G_OFF + tid] = 0.f;
  if (tid < BB * DIM) out[tid] = 0.f;
  int d0 = dc * 32;
  float acc = (dc == 0) ? qkv_b[n] : 0.f;
#pragma unroll 8
  for (int d = d0; d < d0 + 32; ++d) {
    float t0 = cls[d] + pos[d];           // uniform -> scalar load
    acc += t0 * qkv_w[(size_t)d * W3 + n];
  }
  ws[QP_OFF + dc * DIM + n] = acc;
}

// K2: r[h][d] = SCALE * (Wk[d, h-slice] . q[h-slice]); q from summing the 64
// k1 partials. Writes bf16 hi/lo r + atomic gamma. grid (16 dtile, 16 h), 128.
__global__ __launch_bounds__(128) void k2_r(
    const float* __restrict__ qkv_w, const float* __restrict__ pos,
    const float* __restrict__ cls, float* __restrict__ ws) {
  __shared__ float qs[HD];
  int h = blockIdx.y;
  int d = blockIdx.x * 128 + threadIdx.x;
  float qa = 0.f;
#pragma unroll 8
  for (int c = 0; c < 64; ++c)
    qa += ws[QP_OFF + c * DIM + h * HD + threadIdx.x];
  qs[threadIdx.x] = qa;
  __syncthreads();
  const float4* w4 = reinterpret_cast<const float4*>(
      qkv_w + (size_t)d * W3 + DIM + h * HD);
  float acc = 0.f;
#pragma unroll 8
  for (int e4 = 0; e4 < 32; ++e4) {
    float4 w = w4[e4];
    acc += qs[e4*4+0]*w.x + qs[e4*4+1]*w.y + qs[e4*4+2]*w.z + qs[e4*4+3]*w.w;
  }
  float r = acc * SCALE;
  int i = h * DIM + d;
  short* rb = (short*)(ws + RB_OFF);
  rb[i] = bf_hi(r);
  rb[NH * DIM + i] = bf_hi(r - bf_hif(r));
  float g = (cls[d] + pos[d]) * r;        // fused gamma partial
  for (int m = 1; m < 64; m <<= 1) g += __shfl_xor(g, m, 64);
  if ((threadIdx.x & 63) == 0) atomicAdd(&ws[G_OFF + h], g);
}

// K3: scores[b,h,j>=1] via MFMA, 3-term hi/lo (R9-proven compute; plain
// per-ks partial stores). grid (8 jt2, 16 b, 4 ks), 256 thr = 4 waves.
__global__ __launch_bounds__(256) void k3_scores_mfma(
    const float* __restrict__ x, const float* __restrict__ pos,
    float* __restrict__ ws) {
  int jt2 = blockIdx.x, b = blockIdx.y, ks = blockIdx.z;
  int t = threadIdx.x;
  int w = t >> 6, l = t & 63;
  int jt = jt2 * 4 + w;
  int m16 = l & 15, kg = l >> 4;
  int jrow = 1 + jt * 16 + m16;
  int jc = jrow < SEQ ? jrow : (SEQ - 1);   // clamp; jrow==512 masked at store
  const size_t xrow = (size_t)b * CC * DD * 256 + (size_t)(jc - 1) * 256;
  const short* rh = (const short*)(ws + RB_OFF);
  const short* rl = rh + NH * DIM;
  floatx4 acc = {0.f, 0.f, 0.f, 0.f};
#pragma unroll 2
  for (int kk = ks * 16; kk < ks * 16 + 16; ++kk) {
    int d0 = kk * 32 + kg * 8;
    int c = d0 >> 8, doff = d0 & 255;
    const float4* xp = reinterpret_cast<const float4*>(
        x + xrow + (size_t)c * DD * 256 + doff);
    const float4* pp = reinterpret_cast<const float4*>(
        pos + (size_t)jc * DIM + d0);
    float4 xa = xp[0], xb = xp[1];
    float4 pa = pp[0], pb = pp[1];
    float f[8] = {xa.x + pa.x, xa.y + pa.y, xa.z + pa.z, xa.w + pa.w,
                  xb.x + pb.x, xb.y + pb.y, xb.z + pb.z, xb.w + pb.w};
    short8 ahi, alo;
#pragma unroll
    for (int i = 0; i < 8; ++i) {
      ahi[i] = bf_hi(f[i]);
      alo[i] = bf_hi(f[i] - bf_hif(f[i]));   // f-hi exact, then truncate
    }
    short8 bhi = *reinterpret_cast<const short8*>(rh + m16 * DIM + d0);
    short8 blo = *reinterpret_cast<const short8*>(rl + m16 * DIM + d0);
    acc = __builtin_amdgcn_mfma_f32_16x16x32_bf16(ahi, bhi, acc, 0, 0, 0);
    acc = __builtin_amdgcn_mfma_f32_16x16x32_bf16(ahi, blo, acc, 0, 0, 0);
    acc = __builtin_amdgcn_mfma_f32_16x16x32_bf16(alo, bhi, acc, 0, 0, 0);
  }
  // C layout: col(h) = l&15, row(j) = (l>>4)*4 + reg  [m89-verified]
  int h = m16;
#pragma unroll
  for (int reg = 0; reg < 4; ++reg) {
    int row = kg * 4 + reg;
    int j = 1 + jt * 16 + row;
    if (j < SEQ)
      ws[SCP_OFF + (size_t)ks * SCPSZ + (size_t)(b * NH + h) * SEQ + j] =
          acc[reg];
  }
}

// K4: softmax per (b,h): sum 4 score partials + gamma -> p fp32.
// grid (16 h, 16 b) x 64 thr.
__global__ __launch_bounds__(64) void k4_softmax(float* __restrict__ ws) {
  int h = blockIdx.x, b = blockIdx.y, l = threadIdx.x;
  const float* sc0 = ws + SCP_OFF + (size_t)(b * NH + h) * SEQ;
  float gam = ws[G_OFF + h];
  float s[8];
#pragma unroll
  for (int i = 0; i < 8; ++i) {
    int j = i * 64 + l;
    s[i] = sc0[j] + sc0[SCPSZ + j] + sc0[2 * SCPSZ + j] + sc0[3 * SCPSZ + j];
  }
  if (l == 0) s[0] = gam;                 // j=0 slot holds the cls score
  float mx = s[0];
#pragma unroll
  for (int i = 1; i < 8; ++i) mx = fmaxf(mx, s[i]);
  for (int m = 1; m < 64; m <<= 1) mx = fmaxf(mx, __shfl_xor(mx, m, 64));
  float e[8], sum = 0.f;
#pragma unroll
  for (int i = 0; i < 8; ++i) { e[i] = __expf(s[i] - mx); sum += e[i]; }
  for (int m = 1; m < 64; m <<= 1) sum += __shfl_xor(sum, m, 64);
  float inv = 1.f / sum;
  float* pf = ws + PF_OFF + (size_t)(b * NH + h) * SEQ;
#pragma unroll
  for (int i = 0; i < 8; ++i) pf[i * 64 + l] = e[i] * inv;
}

// K5: u (vector FMA). Block (dt 0..3, b, js 0..7): d-range 512, j-range 64.
// Lane owns a d-pair (float2 coalesced x read; x read exactly once across
// grid); p staged from PF (4 KB) to LDS, broadcast via uniform b128 reads.
// Writes u js-partials (plain). grid (4 dt, 16 b, 8 js), 256 thr.
__global__ __launch_bounds__(256) void k5_pv(
    const float* __restrict__ x, const float* __restrict__ pos,
    const float* __restrict__ cls, float* __restrict__ ws) {
  int dt = blockIdx.x, b = blockIdx.y, js = blockIdx.z, t = threadIdx.x;
  __shared__ __attribute__((aligned(16))) float pT[64][20];  // [j-local][h]
  for (int s = t; s < 1024; s += 256) {
    int h = s >> 6, jl = s & 63;
    pT[jl][h] = ws[PF_OFF + (size_t)(b * NH + h) * SEQ + js * 64 + jl];
  }
  __syncthreads();
  int d = dt * 512 + t * 2;
  int c = d >> 8, doff = d & 255;
  const float* xcol = x + (size_t)b * CC * DD * 256 + (size_t)c * DD * 256 + doff;
  floatx2 acc[16];
#pragma unroll
  for (int h = 0; h < 16; ++h) acc[h] = (floatx2){0.f, 0.f};
#pragma unroll 4
  for (int jl = 0; jl < 64; ++jl) {
    int j = js * 64 + jl;
    floatx2 pv = *reinterpret_cast<const floatx2*>(pos + (size_t)j * DIM + d);
    floatx2 xv = (j == 0)
        ? *reinterpret_cast<const floatx2*>(cls + d)
        : *reinterpret_cast<const floatx2*>(xcol + (size_t)(j - 1) * 256);
    floatx2 tok = xv + pv;
#pragma unroll
    for (int h4 = 0; h4 < 4; ++h4) {
      floatx4 p4 = *reinterpret_cast<const floatx4*>(&pT[jl][h4 * 4]);
      acc[h4 * 4 + 0] += p4.x * tok;
      acc[h4 * 4 + 1] += p4.y * tok;
      acc[h4 * 4 + 2] += p4.z * tok;
      acc[h4 * 4 + 3] += p4.w * tok;
    }
  }
  float* ub = ws + UP_OFF + (size_t)(js * 16 + b) * 16 * 2048 + d;
#pragma unroll
  for (int h = 0; h < 16; ++h)
    *reinterpret_cast<floatx2*>(ub + (size_t)h * 2048) = acc[h];
}

// K6: ao partials. Block (nt, ks 0..31): m-range 256 (heads nt*2, nt*2+1),
// d-range 64. Stage u (summing 8 js-partials) to LDS [hh][dd][b]; loop dd:
// coalesced Wv column load + 16 FMA via uniform b128 broadcast. Plain store
// aop[ks][b][m]. grid (8 nt, 32 ks), 256 thr.
__global__ __launch_bounds__(256) void k6_ao(
    const float* __restrict__ qkv_w, const float* __restrict__ qkv_b,
    float* __restrict__ ws) {
  int nt = blockIdx.x, ks = blockIdx.y, t = threadIdx.x;
  int m = nt * 256 + t;
  int h0 = nt * 2;
  __shared__ __attribute__((aligned(16))) float us[2][64][20];
  for (int s = t; s < 2048; s += 256) {
    int dd = s & 63, bb = (s >> 6) & 15, hh = s >> 10;
    float a = 0.f;
#pragma unroll
    for (int js = 0; js < 8; ++js)
      a += ws[UP_OFF + (size_t)(js * 16 + bb) * 16 * 2048 +
              (size_t)(h0 + hh) * 2048 + ks * 64 + dd];
    us[hh][dd][bb] = a;
  }
  __syncthreads();
  int hl = t >> 7;
  float acc[BB];
#pragma unroll
  for (int bb = 0; bb < BB; ++bb) acc[bb] = 0.f;
  const float* wcol = qkv_w + (size_t)(ks * 64) * W3 + 2 * DIM + m;
#pragma unroll 4
  for (int dd = 0; dd < 64; ++dd) {
    float wv = wcol[(size_t)dd * W3];
    floatx4 u0 = *reinterpret_cast<const floatx4*>(&us[hl][dd][0]);
    floatx4 u1 = *reinterpret_cast<const floatx4*>(&us[hl][dd][4]);
    floatx4 u2 = *reinterpret_cast<const floatx4*>(&us[hl][dd][8]);
    floatx4 u3 = *reinterpret_cast<const floatx4*>(&us[hl][dd][12]);
    acc[0]  += u0.x * wv; acc[1]  += u0.y * wv; acc[2]  += u0.z * wv; acc[3]  += u0.w * wv;
    acc[4]  += u1.x * wv; acc[5]  += u1.y * wv; acc[6]  += u1.z * wv; acc[7]  += u1.w * wv;
    acc[8]  += u2.x * wv; acc[9]  += u2.y * wv; acc[10] += u2.z * wv; acc[11] += u2.w * wv;
    acc[12] += u3.x * wv; acc[13] += u3.y * wv; acc[14] += u3.z * wv; acc[15] += u3.w * wv;
  }
  float bias = (ks == 0) ? qkv_b[2 * DIM + m] : 0.f;
#pragma unroll
  for (int bb = 0; bb < BB; ++bb)
    ws[AOP_OFF + (size_t)(ks * 16 + bb) * 2048 + m] = acc[bb] + bias;
}

// K7: out. Block (nt, ms 0..31): n-range 256, m-range 64. Stage ao (summing
// 32 ks-partials) to LDS [mm][b]; loop mm: coalesced proj load + 16 FMA via
// uniform b128 broadcast; atomicAdd into out (zeroed by k1).
// grid (8 nt, 32 ms), 256 thr.
__global__ __launch_bounds__(256) void k7_out(
    const float* __restrict__ proj_w, const float* __restrict__ proj_b,
    const float* __restrict__ ws, float* __restrict__ out) {
  int nt = blockIdx.x, ms = blockIdx.y, t = threadIdx.x;
  int n = nt * 256 + t;
  int m0 = ms * 64;
  __shared__ __attribute__((aligned(16))) float as[64][20];
  for (int s = t; s < 1024; s += 256) {
    int mm = s & 63, bb = s >> 6;
    float a = 0.f;
#pragma unroll
    for (int ks = 0; ks < 32; ++ks)
      a += ws[AOP_OFF + (size_t)(ks * 16 + bb) * 2048 + m0 + mm];
    as[mm][bb] = a;
  }
  __syncthreads();
  float acc[BB];
#pragma unroll
  for (int bb = 0; bb < BB; ++bb) acc[bb] = 0.f;
  const float* wcol = proj_w + (size_t)m0 * DIM + n;
#pragma unroll 4
  for (int mm = 0; mm < 64; ++mm) {
    float wv = wcol[(size_t)mm * DIM];
    floatx4 a0 = *reinterpret_cast<const floatx4*>(&as[mm][0]);
    floatx4 a1 = *reinterpret_cast<const floatx4*>(&as[mm][4]);
    floatx4 a2 = *reinterpret_cast<const floatx4*>(&as[mm][8]);
    floatx4 a3 = *reinterpret_cast<const floatx4*>(&as[mm][12]);
    acc[0]  += a0.x * wv; acc[1]  += a0.y * wv; acc[2]  += a0.z * wv; acc[3]  += a0.w * wv;
    acc[4]  += a1.x * wv; acc[5]  += a1.y * wv; acc[6]  += a1.z * wv; acc[7]  += a1.w * wv;
    acc[8]  += a2.x * wv; acc[9]  += a2.y * wv; acc[10] += a2.z * wv; acc[11] += a2.w * wv;
    acc[12] += a3.x * wv; acc[13] += a3.y * wv; acc[14] += a3.z * wv; acc[15] += a3.w * wv;
  }
  float bias = (ms == 0) ? proj_b[n] : 0.f;
#pragma unroll
  for (int bb = 0; bb < BB; ++bb)
    atomicAdd(&out[bb * DIM + n], acc[bb] + bias);
}

extern "C" void kernel_launch(void* const* d_in, const int* in_sizes, int n_in,
                              void* d_out, int out_size, void* d_ws, size_t ws_size,
                              hipStream_t stream) {
  const float* x      = (const float*)d_in[0];
  const float* pos    = (const float*)d_in[1];
  const float* cls    = (const float*)d_in[2];
  const float* qkv_w  = (const float*)d_in[3];
  const float* qkv_b  = (const float*)d_in[4];
  const float* proj_w = (const float*)d_in[5];
  const float* proj_b = (const float*)d_in[6];
  float* ws  = (float*)d_ws;
  float* out = (float*)d_out;

  k1_q          <<<dim3(8, 64),    256, 0, stream>>>(pos, cls, qkv_w, qkv_b, ws, out);
  k2_r          <<<dim3(16, 16),   128, 0, stream>>>(qkv_w, pos, cls, ws);
  k3_scores_mfma<<<dim3(8, 16, 4), 256, 0, stream>>>(x, pos, ws);
  k4_softmax    <<<dim3(16, 16),    64, 0, stream>>>(ws);
  k5_pv         <<<dim3(4, 16, 8), 256, 0, stream>>>(x, pos, cls, ws);
  k6_ao         <<<dim3(8, 32),    256, 0, stream>>>(qkv_w, qkv_b, ws);
  k7_out        <<<dim3(8, 32),    256, 0, stream>>>(proj_w, proj_b, ws, out);
}